// Round 1
// baseline (1269.551 us; speedup 1.0000x reference)
//
#include <hip/hip_runtime.h>
#include <hip/hip_bf16.h>
#include <math.h>

#define L_LAYERS 12
#define BATCH 8
#define SEQ 2048
#define HID 1024
#define DGATE 256
#define KTOT (L_LAYERS * HID)   // 12288
#define MTOT (BATCH * SEQ)      // 16384

typedef __attribute__((ext_vector_type(4))) float f32x4;
typedef __attribute__((ext_vector_type(8))) short bf16x8;

static __device__ __forceinline__ unsigned short f2bf(float x) {
    __hip_bfloat16 h = __float2bfloat16(x);
    return *reinterpret_cast<unsigned short*>(&h);
}

// ---------------- pooling: pooled_sum[l,b,h] = sum_s layer_outputs[l,b,s,h] ----------------
__global__ void pool_kernel(const float* __restrict__ lo, float* __restrict__ pooled) {
    int lb = blockIdx.x;           // l*8+b, 0..95
    int sc = blockIdx.y;           // 0..15
    int t = threadIdx.x;           // 0..255, handles h = 4t..4t+3
    const float4* src = reinterpret_cast<const float4*>(lo + (size_t)lb * SEQ * HID);
    float4 acc = {0.f, 0.f, 0.f, 0.f};
    int s0 = sc * 128;
    #pragma unroll 4
    for (int s = s0; s < s0 + 128; ++s) {
        float4 v = src[(size_t)s * 256 + t];
        acc.x += v.x; acc.y += v.y; acc.z += v.z; acc.w += v.w;
    }
    float* dst = pooled + (size_t)lb * HID + t * 4;
    atomicAdd(dst + 0, acc.x);
    atomicAdd(dst + 1, acc.y);
    atomicAdd(dst + 2, acc.z);
    atomicAdd(dst + 3, acc.w);
}

// ---------------- gate MLP: one block per (l,b) ----------------
__global__ void gate_kernel(const float* __restrict__ pooled, const float* __restrict__ W1,
                            const float* __restrict__ b1, const float* __restrict__ lnw,
                            const float* __restrict__ lnb, const float* __restrict__ W2,
                            const float* __restrict__ b2, float* __restrict__ gate) {
    int lb = blockIdx.x;
    int l = lb >> 3;
    __shared__ float sp[HID];
    __shared__ float red[256];
    __shared__ float stat[2];
    int t = threadIdx.x;
    for (int i = t; i < HID; i += 256) sp[i] = pooled[(size_t)lb * HID + i] * (1.0f / 2048.0f);
    __syncthreads();
    const float* w1 = W1 + (size_t)l * HID * DGATE + t;
    float h = b1[l * DGATE + t];
    for (int hh = 0; hh < HID; ++hh) h = fmaf(sp[hh], w1[(size_t)hh * DGATE], h);
    // mean
    red[t] = h; __syncthreads();
    for (int o = 128; o > 0; o >>= 1) { if (t < o) red[t] += red[t + o]; __syncthreads(); }
    if (t == 0) stat[0] = red[0] * (1.0f / 256.0f);
    __syncthreads();
    float mu = stat[0];
    float c = h - mu;
    red[t] = c * c; __syncthreads();
    for (int o = 128; o > 0; o >>= 1) { if (t < o) red[t] += red[t + o]; __syncthreads(); }
    if (t == 0) stat[1] = red[0] * (1.0f / 256.0f);
    __syncthreads();
    float hn = c * rsqrtf(stat[1] + 1e-5f) * lnw[l * DGATE + t] + lnb[l * DGATE + t];
    float hg = hn * 0.5f * (1.0f + erff(hn * 0.70710678118654752f));
    red[t] = hg * W2[l * DGATE + t]; __syncthreads();
    for (int o = 128; o > 0; o >>= 1) { if (t < o) red[t] += red[t + o]; __syncthreads(); }
    if (t == 0) gate[lb] = 1.0f / (1.0f + expf(-(red[0] + b2[l])));
}

// ---------------- prep: m (double softmax), w[l,b]=GAMMA*m*gate, bias[b,k]=sum_l w*proj_b ----------------
__global__ void prep_kernel(const float* __restrict__ cw, const float* __restrict__ U,
                            const float* __restrict__ V, const float* __restrict__ gate,
                            const float* __restrict__ projb, const int* __restrict__ cip,
                            float* __restrict__ wscale, float* __restrict__ bias) {
    __shared__ float sm[L_LAYERS];
    __shared__ float sw[L_LAYERS * BATCH];
    int t = threadIdx.x;
    int ci = cip[0];
    if (t == 0) {
        float m[L_LAYERS];
        for (int i = 0; i < L_LAYERS; ++i) {
            float mm = cw[ci * L_LAYERS + i];
            float man = 0.f;
            for (int j = 0; j < 32; ++j) man = fmaf(U[ci * 32 + j], V[j * L_LAYERS + i], man);
            m[i] = 0.5f * mm + 0.5f * man;
        }
        for (int rep = 0; rep < 2; ++rep) {
            float mx = -1e30f;
            for (int i = 0; i < L_LAYERS; ++i) mx = fmaxf(mx, m[i]);
            float s = 0.f;
            for (int i = 0; i < L_LAYERS; ++i) { m[i] = expf(m[i] - mx); s += m[i]; }
            float inv = 1.0f / s;
            for (int i = 0; i < L_LAYERS; ++i) m[i] *= inv;
        }
        for (int i = 0; i < L_LAYERS; ++i) sm[i] = m[i];
    }
    __syncthreads();
    if (t < L_LAYERS * BATCH) {
        int l = t >> 3;
        float w = 0.9f * sm[l] * gate[t];
        sw[t] = w;
        wscale[t] = w;
    }
    __syncthreads();
    for (int i = t; i < BATCH * HID; i += 256) {
        int b = i >> 10, k = i & 1023;
        float acc = 0.f;
        for (int l = 0; l < L_LAYERS; ++l) acc = fmaf(sw[l * BATCH + b], projb[l * HID + k], acc);
        bias[i] = acc;
    }
}

// ---------------- transpose+convert proj_W (KTOT x HID fp32) -> Bt[n][k] bf16 ----------------
__global__ void transB_kernel(const float* __restrict__ W, unsigned short* __restrict__ Bt) {
    __shared__ unsigned short tile[64][72];   // [n_local][k_local], pitch 72 (144B, 16B-aligned rows)
    int k0 = blockIdx.x * 64, n0 = blockIdx.y * 64;
    int t = threadIdx.x;
    #pragma unroll
    for (int p = 0; p < 4; ++p) {
        int r = (t >> 4) + p * 16;        // k_local
        int c = (t & 15) * 4;             // n_local
        float4 v = *reinterpret_cast<const float4*>(W + (size_t)(k0 + r) * HID + n0 + c);
        tile[c + 0][r] = f2bf(v.x);
        tile[c + 1][r] = f2bf(v.y);
        tile[c + 2][r] = f2bf(v.z);
        tile[c + 3][r] = f2bf(v.w);
    }
    __syncthreads();
    #pragma unroll
    for (int p = 0; p < 2; ++p) {
        int idx = t + p * 256;
        int nl = idx >> 3;
        int kc = (idx & 7) * 8;
        uint4 v = *reinterpret_cast<const uint4*>(&tile[nl][kc]);
        *reinterpret_cast<uint4*>(Bt + (size_t)(n0 + nl) * KTOT + k0 + kc) = v;
    }
}

// ---------------- main fused GEMM: C = (w-scaled A) @ Bt^T + bias + residual ----------------
#define BM 128
#define BN 128
#define BK 32
#define LDK 40   // padded LDS pitch in bf16 elems (80B rows -> 2-way-conflict-free b128 reads)
#define NT (KTOT / BK)   // 384

__global__ __launch_bounds__(256, 2) void gemm_kernel(
    const float* __restrict__ lo,             // layer_outputs (L,B,S,H) fp32
    const unsigned short* __restrict__ Btp,   // Bt[n][k] bf16, n<1024, k<12288
    const float* __restrict__ wsc,            // [12][8]
    const float* __restrict__ biasb,          // [8][1024]
    const int* __restrict__ cip,
    float* __restrict__ out)                  // (B,S,H) fp32
{
    __shared__ unsigned short lA[2][BM * LDK];
    __shared__ unsigned short lB[2][BN * LDK];
    __shared__ float sw[L_LAYERS];

    int t = threadIdx.x;
    int bx = blockIdx.x;          // n-tile 0..7
    int by = blockIdx.y;          // m-tile 0..127
    int b = by >> 4;
    int s0 = (by & 15) * BM;
    int n0 = bx * BN;

    if (t < L_LAYERS) sw[t] = wsc[t * BATCH + b];
    __syncthreads();

    int wid = t >> 6, lane = t & 63;
    int wr = wid >> 1, wc = wid & 1;
    int m16 = lane & 15, kb = lane >> 4;
    int aoff[4], boff[4];
    #pragma unroll
    for (int i = 0; i < 4; ++i) {
        aoff[i] = (wr * 64 + i * 16 + m16) * LDK + kb * 8;
        boff[i] = (wc * 64 + i * 16 + m16) * LDK + kb * 8;
    }

    f32x4 acc[4][4];
    #pragma unroll
    for (int i = 0; i < 4; ++i)
        #pragma unroll
        for (int j = 0; j < 4; ++j)
            acc[i][j] = (f32x4){0.f, 0.f, 0.f, 0.f};

    // staging registers
    float4 ra[4];
    uint4 rb[2];

    // per-thread A assignment: f = t + 256*i -> row=f/8, col4=(f%8)*4
    // per-thread B assignment: idx = t + 256*p -> rowB=idx/4, q=idx%4 (8 bf16 each)
    auto load_tile = [&](int tk) {
        int l = tk >> 5;
        int hk = (tk & 31) << 5;
        const float* Ab = lo + (((size_t)l * BATCH + b) * SEQ + s0) * HID + hk;
        #pragma unroll
        for (int i = 0; i < 4; ++i) {
            int f = t + (i << 8);
            int row = f >> 3, c4 = (f & 7) << 2;
            ra[i] = *reinterpret_cast<const float4*>(Ab + (size_t)row * HID + c4);
        }
        const unsigned short* Bb = Btp + (size_t)l * HID + hk;
        #pragma unroll
        for (int p = 0; p < 2; ++p) {
            int idx = t + (p << 8);
            int rowB = idx >> 2, q = idx & 3;
            rb[p] = *reinterpret_cast<const uint4*>(Bb + (size_t)(n0 + rowB) * KTOT + q * 8);
        }
    };
    auto write_tile = [&](int tk, int buf) {
        int l = tk >> 5;
        float scl = sw[l];
        #pragma unroll
        for (int i = 0; i < 4; ++i) {
            int f = t + (i << 8);
            int row = f >> 3, c4 = (f & 7) << 2;
            unsigned int u0 = (unsigned int)f2bf(ra[i].x * scl) | ((unsigned int)f2bf(ra[i].y * scl) << 16);
            unsigned int u1 = (unsigned int)f2bf(ra[i].z * scl) | ((unsigned int)f2bf(ra[i].w * scl) << 16);
            uint2 u = {u0, u1};
            *reinterpret_cast<uint2*>(&lA[buf][row * LDK + c4]) = u;
        }
        #pragma unroll
        for (int p = 0; p < 2; ++p) {
            int idx = t + (p << 8);
            int rowB = idx >> 2, q = idx & 3;
            *reinterpret_cast<uint4*>(&lB[buf][rowB * LDK + q * 8]) = rb[p];
        }
    };

    load_tile(0);
    write_tile(0, 0);
    __syncthreads();

    for (int tk = 0; tk < NT; ++tk) {
        int cur = tk & 1;
        bool more = (tk + 1) < NT;
        if (more) load_tile(tk + 1);

        bf16x8 av[4], bv[4];
        #pragma unroll
        for (int i = 0; i < 4; ++i) av[i] = *reinterpret_cast<const bf16x8*>(&lA[cur][aoff[i]]);
        #pragma unroll
        for (int i = 0; i < 4; ++i) bv[i] = *reinterpret_cast<const bf16x8*>(&lB[cur][boff[i]]);
        #pragma unroll
        for (int fm = 0; fm < 4; ++fm)
            #pragma unroll
            for (int fn = 0; fn < 4; ++fn)
                acc[fm][fn] = __builtin_amdgcn_mfma_f32_16x16x32_bf16(av[fm], bv[fn], acc[fm][fn], 0, 0, 0);

        if (more) write_tile(tk + 1, cur ^ 1);
        __syncthreads();
    }

    // epilogue: out = acc + bias[b,col] + layer_outputs[ci,b,s,col]
    int ci = cip[0];
    const float* resid = lo + (((size_t)ci * BATCH + b) * SEQ + s0) * HID;
    float* op = out + ((size_t)b * SEQ + s0) * HID;
    #pragma unroll
    for (int fn = 0; fn < 4; ++fn) {
        int col = n0 + wc * 64 + fn * 16 + m16;
        float bs = biasb[b * HID + col];
        #pragma unroll
        for (int fm = 0; fm < 4; ++fm) {
            int rbase = wr * 64 + fm * 16 + kb * 4;
            #pragma unroll
            for (int r = 0; r < 4; ++r) {
                float v = acc[fm][fn][r] + bs + resid[(size_t)(rbase + r) * HID + col];
                op[(size_t)(rbase + r) * HID + col] = v;
            }
        }
    }
}

extern "C" void kernel_launch(void* const* d_in, const int* in_sizes, int n_in,
                              void* d_out, int out_size, void* d_ws, size_t ws_size,
                              hipStream_t stream) {
    const float* lo  = (const float*)d_in[0];
    const float* cw  = (const float*)d_in[1];
    const float* mU  = (const float*)d_in[2];
    const float* mV  = (const float*)d_in[3];
    const float* W1  = (const float*)d_in[4];
    const float* b1  = (const float*)d_in[5];
    const float* lnw = (const float*)d_in[6];
    const float* lnb = (const float*)d_in[7];
    const float* W2  = (const float*)d_in[8];
    const float* b2  = (const float*)d_in[9];
    const float* pW  = (const float*)d_in[10];
    const float* pb  = (const float*)d_in[11];
    const int*   ci  = (const int*)d_in[12];
    float* out = (float*)d_out;

    float* pooled = (float*)d_ws;              // 98304 f
    float* gateb  = pooled + 98304;            // 96 f
    float* wsc    = gateb + 96;                // 96 f
    float* biasb  = wsc + 96;                  // 8192 f
    unsigned short* Btp = (unsigned short*)((char*)d_ws + 458752);  // 25165824 B

    hipMemsetAsync(pooled, 0, 98304 * sizeof(float), stream);
    pool_kernel<<<dim3(96, 16), 256, 0, stream>>>(lo, pooled);
    gate_kernel<<<96, 256, 0, stream>>>(pooled, W1, b1, lnw, lnb, W2, b2, gateb);
    prep_kernel<<<1, 256, 0, stream>>>(cw, mU, mV, gateb, pb, ci, wsc, biasb);
    transB_kernel<<<dim3(192, 16), 256, 0, stream>>>(pW, Btp);
    gemm_kernel<<<dim3(8, 128), 256, 0, stream>>>(lo, Btp, wsc, biasb, ci, out);
}

// Round 2
// 813.914 us; speedup vs baseline: 1.5598x; 1.5598x over previous
//
#include <hip/hip_runtime.h>
#include <hip/hip_bf16.h>
#include <math.h>

#define L_LAYERS 12
#define BATCH 8
#define SEQ 2048
#define HID 1024
#define DGATE 256
#define KTOT (L_LAYERS * HID)   // 12288
#define MTOT (BATCH * SEQ)      // 16384

typedef __attribute__((ext_vector_type(4))) float f32x4;
typedef __attribute__((ext_vector_type(8))) short bf16x8;
typedef unsigned short ushortT;

static __device__ __forceinline__ unsigned short f2bf(float x) {
    __hip_bfloat16 h = __float2bfloat16(x);
    return *reinterpret_cast<unsigned short*>(&h);
}

// ---------------- pool (+ optional bf16 convert of A) ----------------
__global__ void pool_convert_kernel(const float* __restrict__ lo, float* __restrict__ pooled,
                                    ushortT* __restrict__ Abf, int doConv) {
    int lb = blockIdx.x;           // l*8+b
    int sc = blockIdx.y;           // 0..15
    int t = threadIdx.x;           // h = 4t..4t+3
    const float4* src = reinterpret_cast<const float4*>(lo + (size_t)lb * SEQ * HID);
    ushortT* dstb = Abf + (size_t)lb * SEQ * HID;
    float4 acc = {0.f, 0.f, 0.f, 0.f};
    int s0 = sc * 128;
    if (doConv) {
        #pragma unroll 4
        for (int s = s0; s < s0 + 128; ++s) {
            float4 v = src[(size_t)s * 256 + t];
            acc.x += v.x; acc.y += v.y; acc.z += v.z; acc.w += v.w;
            unsigned int u0 = (unsigned int)f2bf(v.x) | ((unsigned int)f2bf(v.y) << 16);
            unsigned int u1 = (unsigned int)f2bf(v.z) | ((unsigned int)f2bf(v.w) << 16);
            uint2 uu = {u0, u1};
            *reinterpret_cast<uint2*>(dstb + (size_t)s * HID + t * 4) = uu;
        }
    } else {
        #pragma unroll 4
        for (int s = s0; s < s0 + 128; ++s) {
            float4 v = src[(size_t)s * 256 + t];
            acc.x += v.x; acc.y += v.y; acc.z += v.z; acc.w += v.w;
        }
    }
    float* dst = pooled + (size_t)lb * HID + t * 4;
    atomicAdd(dst + 0, acc.x);
    atomicAdd(dst + 1, acc.y);
    atomicAdd(dst + 2, acc.z);
    atomicAdd(dst + 3, acc.w);
}

// ---------------- gate MLP: one block per (l,b) ----------------
__global__ void gate_kernel(const float* __restrict__ pooled, const float* __restrict__ W1,
                            const float* __restrict__ b1, const float* __restrict__ lnw,
                            const float* __restrict__ lnb, const float* __restrict__ W2,
                            const float* __restrict__ b2, float* __restrict__ gate) {
    int lb = blockIdx.x;
    int l = lb >> 3;
    __shared__ float sp[HID];
    __shared__ float red[256];
    __shared__ float stat[2];
    int t = threadIdx.x;
    for (int i = t; i < HID; i += 256) sp[i] = pooled[(size_t)lb * HID + i] * (1.0f / 2048.0f);
    __syncthreads();
    const float* w1 = W1 + (size_t)l * HID * DGATE + t;
    float h = b1[l * DGATE + t];
    for (int hh = 0; hh < HID; ++hh) h = fmaf(sp[hh], w1[(size_t)hh * DGATE], h);
    red[t] = h; __syncthreads();
    for (int o = 128; o > 0; o >>= 1) { if (t < o) red[t] += red[t + o]; __syncthreads(); }
    if (t == 0) stat[0] = red[0] * (1.0f / 256.0f);
    __syncthreads();
    float mu = stat[0];
    float c = h - mu;
    red[t] = c * c; __syncthreads();
    for (int o = 128; o > 0; o >>= 1) { if (t < o) red[t] += red[t + o]; __syncthreads(); }
    if (t == 0) stat[1] = red[0] * (1.0f / 256.0f);
    __syncthreads();
    float hn = c * rsqrtf(stat[1] + 1e-5f) * lnw[l * DGATE + t] + lnb[l * DGATE + t];
    float hg = hn * 0.5f * (1.0f + erff(hn * 0.70710678118654752f));
    red[t] = hg * W2[l * DGATE + t]; __syncthreads();
    for (int o = 128; o > 0; o >>= 1) { if (t < o) red[t] += red[t + o]; __syncthreads(); }
    if (t == 0) gate[lb] = 1.0f / (1.0f + expf(-(red[0] + b2[l])));
}

// ---------------- prep: m, w, ratios (Horner), bias ----------------
__global__ void prep_kernel(const float* __restrict__ cw, const float* __restrict__ U,
                            const float* __restrict__ V, const float* __restrict__ gate,
                            const float* __restrict__ projb, const int* __restrict__ cip,
                            float* __restrict__ wscale, float* __restrict__ ratio,
                            float* __restrict__ wfin, float* __restrict__ bias) {
    __shared__ float sm[L_LAYERS];
    __shared__ float sw[L_LAYERS * BATCH];
    int t = threadIdx.x;
    int ci = cip[0];
    if (t == 0) {
        float m[L_LAYERS];
        for (int i = 0; i < L_LAYERS; ++i) {
            float mm = cw[ci * L_LAYERS + i];
            float man = 0.f;
            for (int j = 0; j < 32; ++j) man = fmaf(U[ci * 32 + j], V[j * L_LAYERS + i], man);
            m[i] = 0.5f * mm + 0.5f * man;
        }
        for (int rep = 0; rep < 2; ++rep) {
            float mx = -1e30f;
            for (int i = 0; i < L_LAYERS; ++i) mx = fmaxf(mx, m[i]);
            float s = 0.f;
            for (int i = 0; i < L_LAYERS; ++i) { m[i] = expf(m[i] - mx); s += m[i]; }
            float inv = 1.0f / s;
            for (int i = 0; i < L_LAYERS; ++i) m[i] *= inv;
        }
        for (int i = 0; i < L_LAYERS; ++i) sm[i] = m[i];
    }
    __syncthreads();
    if (t < L_LAYERS * BATCH) {
        int l = t >> 3;
        float w = 0.9f * sm[l] * gate[t];
        sw[t] = w;
        wscale[t] = w;
    }
    __syncthreads();
    if (t < BATCH) {
        for (int l = 0; l < L_LAYERS; ++l) {
            float r = (l == 0) ? 1.0f : (sw[(l - 1) * BATCH + t] / sw[l * BATCH + t]);
            ratio[t * 16 + l] = r;
        }
        wfin[t] = sw[(L_LAYERS - 1) * BATCH + t];
    }
    for (int i = t; i < BATCH * HID; i += 256) {
        int b = i >> 10, k = i & 1023;
        float acc = 0.f;
        for (int l = 0; l < L_LAYERS; ++l) acc = fmaf(sw[l * BATCH + b], projb[l * HID + k], acc);
        bias[i] = acc;
    }
}

// ---------------- transpose+convert proj_W (KTOT x HID fp32) -> Bt[n][k] bf16 ----------------
__global__ void transB_kernel(const float* __restrict__ W, ushortT* __restrict__ Bt) {
    __shared__ ushortT tile[64][72];
    int k0 = blockIdx.x * 64, n0 = blockIdx.y * 64;
    int t = threadIdx.x;
    #pragma unroll
    for (int p = 0; p < 4; ++p) {
        int r = (t >> 4) + p * 16;
        int c = (t & 15) * 4;
        float4 v = *reinterpret_cast<const float4*>(W + (size_t)(k0 + r) * HID + n0 + c);
        tile[c + 0][r] = f2bf(v.x);
        tile[c + 1][r] = f2bf(v.y);
        tile[c + 2][r] = f2bf(v.z);
        tile[c + 3][r] = f2bf(v.w);
    }
    __syncthreads();
    #pragma unroll
    for (int p = 0; p < 2; ++p) {
        int idx = t + p * 256;
        int nl = idx >> 3;
        int kc = (idx & 7) * 8;
        uint4 v = *reinterpret_cast<const uint4*>(&tile[nl][kc]);
        *reinterpret_cast<uint4*>(Bt + (size_t)(n0 + nl) * KTOT + k0 + kc) = v;
    }
}

// ---------------- main GEMM: bf16 A (unscaled) via global_load_lds + swizzle; Horner per-layer rescale ----------------
#define BM 128
#define BN 128
#define BK 64
#define NT (KTOT / BK)    // 192

__global__ __launch_bounds__(256, 2) void gemm_kernel(
    const float* __restrict__ lo,             // for residual
    const ushortT* __restrict__ Abf,          // bf16 A, (L,B,S,H)
    const ushortT* __restrict__ Btp,          // bf16 Bt[n][k]
    const float* __restrict__ ratioP,         // [8][16] Horner ratios
    const float* __restrict__ wfinP,          // [8]
    const float* __restrict__ biasb,          // [8][1024]
    const int* __restrict__ cip,
    float* __restrict__ out)
{
    __shared__ ushortT lA[2][BM * BK];   // 2 x 16 KB
    __shared__ ushortT lB[2][BN * BK];   // 2 x 16 KB

    int t = threadIdx.x;
    // XCD-bijective decode: xcd = bid&7 -> each XCD owns one batch b
    int bid = blockIdx.x;
    int xcd = bid & 7, local = bid >> 3;
    int by = xcd * 16 + (local >> 3);
    int bx = local & 7;
    int b = by >> 4;
    int s0 = (by & 15) << 7;
    int n0 = bx << 7;

    int wid = t >> 6, lane = t & 63;
    int wr = wid >> 1, wc = wid & 1;
    int m16 = lane & 15, kb = lane >> 4;

    // staging assignments (chunk = 16B = 8 bf16; tile = 128 rows x 8 chunks)
    int aBase[4], bBase[4], ldsBase[4];
    #pragma unroll
    for (int i = 0; i < 4; ++i) {
        int ci = i * 256 + t;
        int row = ci >> 3, c = ci & 7;
        int sw = c ^ (row & 7);
        aBase[i] = (s0 + row) * HID + sw * 8;
        bBase[i] = (n0 + row) * KTOT + sw * 8;
        ldsBase[i] = i * 2048 + wid * 512;   // shorts; wave-uniform chunk base
    }

    // ds_read fragment offsets (shorts), swizzled
    int aoff[4][2], boff[4][2];
    #pragma unroll
    for (int i = 0; i < 4; ++i) {
        int ra = wr * 64 + i * 16 + m16;
        int rb = wc * 64 + i * 16 + m16;
        #pragma unroll
        for (int kk = 0; kk < 2; ++kk) {
            aoff[i][kk] = ra * 64 + (((kb + 4 * kk) ^ (ra & 7)) * 8);
            boff[i][kk] = rb * 64 + (((kb + 4 * kk) ^ (rb & 7)) * 8);
        }
    }

    f32x4 acc[4][4];
    #pragma unroll
    for (int i = 0; i < 4; ++i)
        #pragma unroll
        for (int j = 0; j < 4; ++j)
            acc[i][j] = (f32x4){0.f, 0.f, 0.f, 0.f};

    auto stage = [&](int buf, int tk2) {
        int l = tk2 >> 4;
        const ushortT* aT = Abf + (size_t)(l * BATCH + b) * (SEQ * HID) + ((tk2 & 15) << 6);
        const ushortT* bT = Btp + ((size_t)tk2 << 6);
        ushortT* la = &lA[buf][0];
        ushortT* lb = &lB[buf][0];
        #pragma unroll
        for (int i = 0; i < 4; ++i) {
            __builtin_amdgcn_global_load_lds(
                (const __attribute__((address_space(1))) void*)(aT + aBase[i]),
                (__attribute__((address_space(3))) void*)(la + ldsBase[i]), 16, 0, 0);
        }
        #pragma unroll
        for (int i = 0; i < 4; ++i) {
            __builtin_amdgcn_global_load_lds(
                (const __attribute__((address_space(1))) void*)(bT + bBase[i]),
                (__attribute__((address_space(3))) void*)(lb + ldsBase[i]), 16, 0, 0);
        }
    };

    stage(0, 0);
    __syncthreads();

    for (int tk = 0; tk < NT; ++tk) {
        int cur = tk & 1;
        if (tk + 1 < NT) stage(cur ^ 1, tk + 1);

        bf16x8 av[4][2], bv[4][2];
        #pragma unroll
        for (int i = 0; i < 4; ++i) {
            av[i][0] = *reinterpret_cast<const bf16x8*>(&lA[cur][aoff[i][0]]);
            av[i][1] = *reinterpret_cast<const bf16x8*>(&lA[cur][aoff[i][1]]);
            bv[i][0] = *reinterpret_cast<const bf16x8*>(&lB[cur][boff[i][0]]);
            bv[i][1] = *reinterpret_cast<const bf16x8*>(&lB[cur][boff[i][1]]);
        }

        if ((tk & 15) == 0 && tk) {           // entering layer l: Horner rescale
            float rr = ratioP[b * 16 + (tk >> 4)];
            #pragma unroll
            for (int i = 0; i < 4; ++i)
                #pragma unroll
                for (int j = 0; j < 4; ++j)
                    acc[i][j] = acc[i][j] * rr;
        }

        #pragma unroll
        for (int kk = 0; kk < 2; ++kk)
            #pragma unroll
            for (int fm = 0; fm < 4; ++fm)
                #pragma unroll
                for (int fn = 0; fn < 4; ++fn)
                    acc[fm][fn] = __builtin_amdgcn_mfma_f32_16x16x32_bf16(av[fm][kk], bv[fn][kk], acc[fm][fn], 0, 0, 0);

        __syncthreads();
    }

    // epilogue: out = acc*w11 + bias + residual
    int ci = cip[0];
    float wf = wfinP[b];
    const float* resid = lo + (((size_t)ci * BATCH + b) * SEQ + s0) * HID;
    float* op = out + ((size_t)b * SEQ + s0) * HID;
    #pragma unroll
    for (int fn = 0; fn < 4; ++fn) {
        int col = n0 + wc * 64 + fn * 16 + m16;
        float bs = biasb[b * HID + col];
        #pragma unroll
        for (int fm = 0; fm < 4; ++fm) {
            int rbase = wr * 64 + fm * 16 + kb * 4;
            #pragma unroll
            for (int r = 0; r < 4; ++r) {
                float v = acc[fm][fn][r] * wf + bs + resid[(size_t)(rbase + r) * HID + col];
                op[(size_t)(rbase + r) * HID + col] = v;
            }
        }
    }
}

// ---------------- fallback GEMM (round-1 proven, fp32 A reg-staged) ----------------
#define LDKF 40
__global__ __launch_bounds__(256, 2) void gemm_fb_kernel(
    const float* __restrict__ lo, const ushortT* __restrict__ Btp,
    const float* __restrict__ wsc, const float* __restrict__ biasb,
    const int* __restrict__ cip, float* __restrict__ out)
{
    __shared__ ushortT lA[2][BM * LDKF];
    __shared__ ushortT lB[2][BN * LDKF];
    __shared__ float sw[L_LAYERS];
    int t = threadIdx.x;
    int bx = blockIdx.x, by = blockIdx.y;
    int b = by >> 4;
    int s0 = (by & 15) * BM;
    int n0 = bx * BN;
    if (t < L_LAYERS) sw[t] = wsc[t * BATCH + b];
    __syncthreads();
    int wid = t >> 6, lane = t & 63;
    int wr = wid >> 1, wc = wid & 1;
    int m16 = lane & 15, kb = lane >> 4;
    int aoff[4], boff[4];
    #pragma unroll
    for (int i = 0; i < 4; ++i) {
        aoff[i] = (wr * 64 + i * 16 + m16) * LDKF + kb * 8;
        boff[i] = (wc * 64 + i * 16 + m16) * LDKF + kb * 8;
    }
    f32x4 acc[4][4];
    #pragma unroll
    for (int i = 0; i < 4; ++i)
        #pragma unroll
        for (int j = 0; j < 4; ++j)
            acc[i][j] = (f32x4){0.f, 0.f, 0.f, 0.f};
    float4 ra[4];
    uint4 rb[2];
    auto load_tile = [&](int tk) {
        int l = tk >> 5;
        int hk = (tk & 31) << 5;
        const float* Ab = lo + (((size_t)l * BATCH + b) * SEQ + s0) * HID + hk;
        #pragma unroll
        for (int i = 0; i < 4; ++i) {
            int f = t + (i << 8);
            int row = f >> 3, c4 = (f & 7) << 2;
            ra[i] = *reinterpret_cast<const float4*>(Ab + (size_t)row * HID + c4);
        }
        const ushortT* Bb = Btp + (size_t)l * HID + hk;
        #pragma unroll
        for (int p = 0; p < 2; ++p) {
            int idx = t + (p << 8);
            int rowB = idx >> 2, q = idx & 3;
            rb[p] = *reinterpret_cast<const uint4*>(Bb + (size_t)(n0 + rowB) * KTOT + q * 8);
        }
    };
    auto write_tile = [&](int tk, int buf) {
        int l = tk >> 5;
        float scl = sw[l];
        #pragma unroll
        for (int i = 0; i < 4; ++i) {
            int f = t + (i << 8);
            int row = f >> 3, c4 = (f & 7) << 2;
            unsigned int u0 = (unsigned int)f2bf(ra[i].x * scl) | ((unsigned int)f2bf(ra[i].y * scl) << 16);
            unsigned int u1 = (unsigned int)f2bf(ra[i].z * scl) | ((unsigned int)f2bf(ra[i].w * scl) << 16);
            uint2 u = {u0, u1};
            *reinterpret_cast<uint2*>(&lA[buf][row * LDKF + c4]) = u;
        }
        #pragma unroll
        for (int p = 0; p < 2; ++p) {
            int idx = t + (p << 8);
            int rowB = idx >> 2, q = idx & 3;
            *reinterpret_cast<uint4*>(&lB[buf][rowB * LDKF + q * 8]) = rb[p];
        }
    };
    load_tile(0);
    write_tile(0, 0);
    __syncthreads();
    for (int tk = 0; tk < KTOT / 32; ++tk) {
        int cur = tk & 1;
        bool more = (tk + 1) < KTOT / 32;
        if (more) load_tile(tk + 1);
        bf16x8 av[4], bv[4];
        #pragma unroll
        for (int i = 0; i < 4; ++i) av[i] = *reinterpret_cast<const bf16x8*>(&lA[cur][aoff[i]]);
        #pragma unroll
        for (int i = 0; i < 4; ++i) bv[i] = *reinterpret_cast<const bf16x8*>(&lB[cur][boff[i]]);
        #pragma unroll
        for (int fm = 0; fm < 4; ++fm)
            #pragma unroll
            for (int fn = 0; fn < 4; ++fn)
                acc[fm][fn] = __builtin_amdgcn_mfma_f32_16x16x32_bf16(av[fm], bv[fn], acc[fm][fn], 0, 0, 0);
        if (more) write_tile(tk + 1, cur ^ 1);
        __syncthreads();
    }
    int ci = cip[0];
    const float* resid = lo + (((size_t)ci * BATCH + b) * SEQ + s0) * HID;
    float* op = out + ((size_t)b * SEQ + s0) * HID;
    #pragma unroll
    for (int fn = 0; fn < 4; ++fn) {
        int col = n0 + wc * 64 + fn * 16 + m16;
        float bs = biasb[b * HID + col];
        #pragma unroll
        for (int fm = 0; fm < 4; ++fm) {
            int rbase = wr * 64 + fm * 16 + kb * 4;
            #pragma unroll
            for (int r = 0; r < 4; ++r) {
                float v = acc[fm][fn][r] + bs + resid[(size_t)(rbase + r) * HID + col];
                op[(size_t)(rbase + r) * HID + col] = v;
            }
        }
    }
}

extern "C" void kernel_launch(void* const* d_in, const int* in_sizes, int n_in,
                              void* d_out, int out_size, void* d_ws, size_t ws_size,
                              hipStream_t stream) {
    const float* lo  = (const float*)d_in[0];
    const float* cw  = (const float*)d_in[1];
    const float* mU  = (const float*)d_in[2];
    const float* mV  = (const float*)d_in[3];
    const float* W1  = (const float*)d_in[4];
    const float* b1  = (const float*)d_in[5];
    const float* lnw = (const float*)d_in[6];
    const float* lnb = (const float*)d_in[7];
    const float* W2  = (const float*)d_in[8];
    const float* b2  = (const float*)d_in[9];
    const float* pW  = (const float*)d_in[10];
    const float* pb  = (const float*)d_in[11];
    const int*   ci  = (const int*)d_in[12];
    float* out = (float*)d_out;

    // ws layout
    float* pooled = (float*)d_ws;                          // 98304 f  (393216 B)
    float* gateb  = pooled + 98304;                        // 96 f
    float* wsc    = gateb + 96;                            // 96 f
    float* ratio  = wsc + 96;                              // 128 f
    float* wfin   = ratio + 128;                           // 8 f
    float* biasb  = wfin + 8;                              // 8192 f
    ushortT* Btp  = (ushortT*)((char*)d_ws + 458752);      // 25165824 B
    ushortT* Abf  = (ushortT*)((char*)d_ws + 25624576);    // 402653184 B
    const size_t need = 25624576ULL + 402653184ULL;

    int fast = (ws_size >= need) ? 1 : 0;

    hipMemsetAsync(pooled, 0, 98304 * sizeof(float), stream);
    pool_convert_kernel<<<dim3(96, 16), 256, 0, stream>>>(lo, pooled, Abf, fast);
    gate_kernel<<<96, 256, 0, stream>>>(pooled, W1, b1, lnw, lnb, W2, b2, gateb);
    prep_kernel<<<1, 256, 0, stream>>>(cw, mU, mV, gateb, pb, ci, wsc, ratio, wfin, biasb);
    transB_kernel<<<dim3(192, 16), 256, 0, stream>>>(pW, Btp);
    if (fast) {
        gemm_kernel<<<dim3(1024), 256, 0, stream>>>(lo, Abf, Btp, ratio, wfin, biasb, ci, out);
    } else {
        gemm_fb_kernel<<<dim3(8, 128), 256, 0, stream>>>(lo, Btp, wsc, biasb, ci, out);
    }
}

// Round 3
// 690.049 us; speedup vs baseline: 1.8398x; 1.1795x over previous
//
#include <hip/hip_runtime.h>
#include <hip/hip_bf16.h>
#include <math.h>

#define L_LAYERS 12
#define BATCH 8
#define SEQ 2048
#define HID 1024
#define DGATE 256
#define KTOT (L_LAYERS * HID)   // 12288
#define MTOT (BATCH * SEQ)      // 16384

typedef __attribute__((ext_vector_type(4))) float f32x4;
typedef __attribute__((ext_vector_type(8))) short bf16x8;
typedef unsigned short ushortT;

static __device__ __forceinline__ unsigned short f2bf(float x) {
    __hip_bfloat16 h = __float2bfloat16(x);
    return *reinterpret_cast<unsigned short*>(&h);
}

// ---------------- pool (+ bf16 convert of A) ----------------
__global__ void pool_convert_kernel(const float* __restrict__ lo, float* __restrict__ pooled,
                                    ushortT* __restrict__ Abf, int doConv) {
    int lb = blockIdx.x;           // l*8+b
    int sc = blockIdx.y;           // 0..15
    int t = threadIdx.x;           // h = 4t..4t+3
    const float4* src = reinterpret_cast<const float4*>(lo + (size_t)lb * SEQ * HID);
    ushortT* dstb = Abf + (size_t)lb * SEQ * HID;
    float4 acc = {0.f, 0.f, 0.f, 0.f};
    int s0 = sc * 128;
    if (doConv) {
        #pragma unroll 4
        for (int s = s0; s < s0 + 128; ++s) {
            float4 v = src[(size_t)s * 256 + t];
            acc.x += v.x; acc.y += v.y; acc.z += v.z; acc.w += v.w;
            unsigned int u0 = (unsigned int)f2bf(v.x) | ((unsigned int)f2bf(v.y) << 16);
            unsigned int u1 = (unsigned int)f2bf(v.z) | ((unsigned int)f2bf(v.w) << 16);
            uint2 uu = {u0, u1};
            *reinterpret_cast<uint2*>(dstb + (size_t)s * HID + t * 4) = uu;
        }
    } else {
        #pragma unroll 4
        for (int s = s0; s < s0 + 128; ++s) {
            float4 v = src[(size_t)s * 256 + t];
            acc.x += v.x; acc.y += v.y; acc.z += v.z; acc.w += v.w;
        }
    }
    float* dst = pooled + (size_t)lb * HID + t * 4;
    atomicAdd(dst + 0, acc.x);
    atomicAdd(dst + 1, acc.y);
    atomicAdd(dst + 2, acc.z);
    atomicAdd(dst + 3, acc.w);
}

// ---------------- gate MLP: one block per (l,b) ----------------
__global__ void gate_kernel(const float* __restrict__ pooled, const float* __restrict__ W1,
                            const float* __restrict__ b1, const float* __restrict__ lnw,
                            const float* __restrict__ lnb, const float* __restrict__ W2,
                            const float* __restrict__ b2, float* __restrict__ gate) {
    int lb = blockIdx.x;
    int l = lb >> 3;
    __shared__ float sp[HID];
    __shared__ float red[256];
    __shared__ float stat[2];
    int t = threadIdx.x;
    for (int i = t; i < HID; i += 256) sp[i] = pooled[(size_t)lb * HID + i] * (1.0f / 2048.0f);
    __syncthreads();
    const float* w1 = W1 + (size_t)l * HID * DGATE + t;
    float h = b1[l * DGATE + t];
    for (int hh = 0; hh < HID; ++hh) h = fmaf(sp[hh], w1[(size_t)hh * DGATE], h);
    red[t] = h; __syncthreads();
    for (int o = 128; o > 0; o >>= 1) { if (t < o) red[t] += red[t + o]; __syncthreads(); }
    if (t == 0) stat[0] = red[0] * (1.0f / 256.0f);
    __syncthreads();
    float mu = stat[0];
    float c = h - mu;
    red[t] = c * c; __syncthreads();
    for (int o = 128; o > 0; o >>= 1) { if (t < o) red[t] += red[t + o]; __syncthreads(); }
    if (t == 0) stat[1] = red[0] * (1.0f / 256.0f);
    __syncthreads();
    float hn = c * rsqrtf(stat[1] + 1e-5f) * lnw[l * DGATE + t] + lnb[l * DGATE + t];
    float hg = hn * 0.5f * (1.0f + erff(hn * 0.70710678118654752f));
    red[t] = hg * W2[l * DGATE + t]; __syncthreads();
    for (int o = 128; o > 0; o >>= 1) { if (t < o) red[t] += red[t + o]; __syncthreads(); }
    if (t == 0) gate[lb] = 1.0f / (1.0f + expf(-(red[0] + b2[l])));
}

// ---------------- prep: m, w, ratios (Horner), bias ----------------
__global__ void prep_kernel(const float* __restrict__ cw, const float* __restrict__ U,
                            const float* __restrict__ V, const float* __restrict__ gate,
                            const float* __restrict__ projb, const int* __restrict__ cip,
                            float* __restrict__ wscale, float* __restrict__ ratio,
                            float* __restrict__ wfin, float* __restrict__ bias) {
    __shared__ float sm[L_LAYERS];
    __shared__ float sw[L_LAYERS * BATCH];
    int t = threadIdx.x;
    int ci = cip[0];
    if (t == 0) {
        float m[L_LAYERS];
        for (int i = 0; i < L_LAYERS; ++i) {
            float mm = cw[ci * L_LAYERS + i];
            float man = 0.f;
            for (int j = 0; j < 32; ++j) man = fmaf(U[ci * 32 + j], V[j * L_LAYERS + i], man);
            m[i] = 0.5f * mm + 0.5f * man;
        }
        for (int rep = 0; rep < 2; ++rep) {
            float mx = -1e30f;
            for (int i = 0; i < L_LAYERS; ++i) mx = fmaxf(mx, m[i]);
            float s = 0.f;
            for (int i = 0; i < L_LAYERS; ++i) { m[i] = expf(m[i] - mx); s += m[i]; }
            float inv = 1.0f / s;
            for (int i = 0; i < L_LAYERS; ++i) m[i] *= inv;
        }
        for (int i = 0; i < L_LAYERS; ++i) sm[i] = m[i];
    }
    __syncthreads();
    if (t < L_LAYERS * BATCH) {
        int l = t >> 3;
        float w = 0.9f * sm[l] * gate[t];
        sw[t] = w;
        wscale[t] = w;
    }
    __syncthreads();
    if (t < BATCH) {
        for (int l = 0; l < L_LAYERS; ++l) {
            float r = (l == 0) ? 1.0f : (sw[(l - 1) * BATCH + t] / sw[l * BATCH + t]);
            ratio[t * 16 + l] = r;
        }
        wfin[t] = sw[(L_LAYERS - 1) * BATCH + t];
    }
    for (int i = t; i < BATCH * HID; i += 256) {
        int b = i >> 10, k = i & 1023;
        float acc = 0.f;
        for (int l = 0; l < L_LAYERS; ++l) acc = fmaf(sw[l * BATCH + b], projb[l * HID + k], acc);
        bias[i] = acc;
    }
}

// ---------------- transpose+convert proj_W (KTOT x HID fp32) -> Bt[n][k] bf16 ----------------
__global__ void transB_kernel(const float* __restrict__ W, ushortT* __restrict__ Bt) {
    __shared__ ushortT tile[64][72];
    int k0 = blockIdx.x * 64, n0 = blockIdx.y * 64;
    int t = threadIdx.x;
    #pragma unroll
    for (int p = 0; p < 4; ++p) {
        int r = (t >> 4) + p * 16;
        int c = (t & 15) * 4;
        float4 v = *reinterpret_cast<const float4*>(W + (size_t)(k0 + r) * HID + n0 + c);
        tile[c + 0][r] = f2bf(v.x);
        tile[c + 1][r] = f2bf(v.y);
        tile[c + 2][r] = f2bf(v.z);
        tile[c + 3][r] = f2bf(v.w);
    }
    __syncthreads();
    #pragma unroll
    for (int p = 0; p < 2; ++p) {
        int idx = t + p * 256;
        int nl = idx >> 3;
        int kc = (idx & 7) * 8;
        uint4 v = *reinterpret_cast<const uint4*>(&tile[nl][kc]);
        *reinterpret_cast<uint4*>(Bt + (size_t)(n0 + nl) * KTOT + k0 + kc) = v;
    }
}

// ================= 256x256 8-phase GEMM (T3+T4+T5), BK=64 as 2 k-half units =================
// LDS (ushort units): A: buf d in [d*16384, +16384), halves of 8192 (16KB each, [256 rows][32 k])
//                     B: +32768 same structure. Total 65536 ushorts = 128 KiB.

#define MM(a, bb, c) __builtin_amdgcn_mfma_f32_16x16x32_bf16(a, bb, c, 0, 0, 0)

#define LDSA(d, h, off) (*(const bf16x8*)(ldsu + (d) * 16384 + (h) * 8192 + (off)))
#define LDSB(d, h, off) (*(const bf16x8*)(ldsu + 32768 + (d) * 16384 + (h) * 8192 + (off)))

#define READ_AB(d, h) { \
    av[0] = LDSA(d, h, aoffm[0]); av[1] = LDSA(d, h, aoffm[1]); \
    av[2] = LDSA(d, h, aoffm[2]); av[3] = LDSA(d, h, aoffm[3]); \
    bv[0] = LDSB(d, h, boffn[0]); bv[1] = LDSB(d, h, boffn[1]); \
    bv[2] = LDSB(d, h, boffn[2]); bv[3] = LDSB(d, h, boffn[3]); }

#define READ_A2(d, h) { \
    av[0] = LDSA(d, h, aoffm[4]); av[1] = LDSA(d, h, aoffm[5]); \
    av[2] = LDSA(d, h, aoffm[6]); av[3] = LDSA(d, h, aoffm[7]); }

#define MFMA16(mb) { \
    acc[(mb)+0][0] = MM(av[0], bv[0], acc[(mb)+0][0]); acc[(mb)+0][1] = MM(av[0], bv[1], acc[(mb)+0][1]); \
    acc[(mb)+0][2] = MM(av[0], bv[2], acc[(mb)+0][2]); acc[(mb)+0][3] = MM(av[0], bv[3], acc[(mb)+0][3]); \
    acc[(mb)+1][0] = MM(av[1], bv[0], acc[(mb)+1][0]); acc[(mb)+1][1] = MM(av[1], bv[1], acc[(mb)+1][1]); \
    acc[(mb)+1][2] = MM(av[1], bv[2], acc[(mb)+1][2]); acc[(mb)+1][3] = MM(av[1], bv[3], acc[(mb)+1][3]); \
    acc[(mb)+2][0] = MM(av[2], bv[0], acc[(mb)+2][0]); acc[(mb)+2][1] = MM(av[2], bv[1], acc[(mb)+2][1]); \
    acc[(mb)+2][2] = MM(av[2], bv[2], acc[(mb)+2][2]); acc[(mb)+2][3] = MM(av[2], bv[3], acc[(mb)+2][3]); \
    acc[(mb)+3][0] = MM(av[3], bv[0], acc[(mb)+3][0]); acc[(mb)+3][1] = MM(av[3], bv[1], acc[(mb)+3][1]); \
    acc[(mb)+3][2] = MM(av[3], bv[2], acc[(mb)+3][2]); acc[(mb)+3][3] = MM(av[3], bv[3], acc[(mb)+3][3]); }

#define BAR_MID \
    __builtin_amdgcn_s_barrier(); \
    asm volatile("s_waitcnt lgkmcnt(0)" ::: "memory"); \
    __builtin_amdgcn_s_setprio(1);

#define BAR_END \
    __builtin_amdgcn_s_setprio(0); \
    __builtin_amdgcn_s_barrier(); \
    __builtin_amdgcn_sched_barrier(0);

#define BAR_END_V(n) \
    __builtin_amdgcn_s_setprio(0); \
    asm volatile("s_waitcnt vmcnt(" #n ")" ::: "memory"); \
    __builtin_amdgcn_s_barrier(); \
    __builtin_amdgcn_sched_barrier(0);

__global__ __launch_bounds__(512, 2) void gemm8_kernel(
    const float* __restrict__ lo,             // residual source
    const ushortT* __restrict__ Abf,          // bf16 A (L,B,S,H)
    const ushortT* __restrict__ Btp,          // bf16 Bt[n][k]
    const float* __restrict__ ratioP,         // [8][16]
    const float* __restrict__ wfinP,          // [8]
    const float* __restrict__ biasb,          // [8][1024]
    const int* __restrict__ cip,
    float* __restrict__ out)
{
    __shared__ ushortT ldsu[65536];           // 128 KiB

    const int tid = threadIdx.x;
    const int wid = tid >> 6, lane = tid & 63;
    const int wm = wid >> 2, wn = wid & 3;

    // XCD-chunked block decode: 256 blocks, xcd = bid&7 gets 8 consecutive m-tiles x 4 n-tiles
    int bid = blockIdx.x;
    int xcd = bid & 7, local = bid >> 3;
    int mt = xcd * 8 + (local >> 2);          // 0..63
    int nt = local & 3;                       // 0..3
    int b = mt >> 3;
    int s0 = (mt & 7) << 8;                   // 256-row tile within batch b
    int n0 = nt << 8;                         // 256-col tile

    // staging per-thread offsets (2 issues of 16B per half-unit)
    int aSrcE[2], bSrcE[2], ldstE[2];
    #pragma unroll
    for (int j = 0; j < 2; ++j) {
        int idx = j * 512 + tid;
        int r = idx >> 2, c = idx & 3;
        aSrcE[j] = (s0 + r) * HID + c * 8;    // element offset within (l,b) plane (col base added later)
        bSrcE[j] = (n0 + r) * KTOT + c * 8;
        ldstE[j] = idx * 8;                   // ushort offset within half-unit
    }

    // ds_read fragment offsets (ushort units within a half-unit)
    int aoffm[8], boffn[4];
    #pragma unroll
    for (int m = 0; m < 8; ++m) {
        int row = wm * 128 + m * 16 + (lane & 15);
        aoffm[m] = row * 32 + (lane >> 4) * 8;
    }
    #pragma unroll
    for (int n = 0; n < 4; ++n) {
        int row = wn * 64 + n * 16 + (lane & 15);
        boffn[n] = row * 32 + (lane >> 4) * 8;
    }

    f32x4 acc[8][4];
    #pragma unroll
    for (int m = 0; m < 8; ++m)
        #pragma unroll
        for (int n = 0; n < 4; ++n)
            acc[m][n] = (f32x4){0.f, 0.f, 0.f, 0.f};

    auto stageA = [&](int d, int h, int kt) {
        int l = kt >> 4;
        const ushortT* src = Abf + (size_t)(l * BATCH + b) * (SEQ * HID) + ((kt & 15) << 6) + (h << 5);
        ushortT* dst = ldsu + d * 16384 + h * 8192;
        #pragma unroll
        for (int j = 0; j < 2; ++j)
            __builtin_amdgcn_global_load_lds(
                (const __attribute__((address_space(1))) void*)(src + aSrcE[j]),
                (__attribute__((address_space(3))) void*)(dst + ldstE[j]), 16, 0, 0);
    };
    auto stageB = [&](int d, int h, int kt) {
        const ushortT* src = Btp + (kt << 6) + (h << 5);
        ushortT* dst = ldsu + 32768 + d * 16384 + h * 8192;
        #pragma unroll
        for (int j = 0; j < 2; ++j)
            __builtin_amdgcn_global_load_lds(
                (const __attribute__((address_space(1))) void*)(src + bSrcE[j]),
                (__attribute__((address_space(3))) void*)(dst + ldstE[j]), 16, 0, 0);
    };

    // prologue: tile0 (4 units) + tile1 (first 3 units); A(1,h1) comes from iter-0 P1
    stageA(0, 0, 0); stageB(0, 0, 0); stageA(0, 1, 0); stageB(0, 1, 0);
    stageB(1, 0, 1); stageA(1, 0, 1); stageB(1, 1, 1);
    asm volatile("s_waitcnt vmcnt(6)" ::: "memory");
    __builtin_amdgcn_s_barrier();
    __builtin_amdgcn_sched_barrier(0);

    bf16x8 av[4], bv[4];

    #pragma unroll 1
    for (int i = 0; i < 95; ++i) {
        int t0 = 2 * i, t1 = 2 * i + 1;
        if (i && !(i & 7)) {                  // entering a new layer: Horner rescale
            float rr = ratioP[b * 16 + (i >> 3)];
            #pragma unroll
            for (int m = 0; m < 8; ++m)
                #pragma unroll
                for (int n = 0; n < 4; ++n)
                    acc[m][n] *= rr;
        }
        // P1
        READ_AB(0, 0); stageA(1, 1, t1);       BAR_MID; MFMA16(0); BAR_END;
        // P2
        READ_A2(0, 0); stageB(0, 0, t0 + 2);   BAR_MID; MFMA16(4); BAR_END;
        // P3
        READ_AB(0, 1); stageA(0, 0, t0 + 2);   BAR_MID; MFMA16(0); BAR_END;
        // P4
        READ_A2(0, 1); stageB(0, 1, t0 + 2);   BAR_MID; MFMA16(4); BAR_END_V(6);
        // P5
        READ_AB(1, 0); stageA(0, 1, t0 + 2);   BAR_MID; MFMA16(0); BAR_END;
        // P6
        READ_A2(1, 0); stageB(1, 0, t1 + 2);   BAR_MID; MFMA16(4); BAR_END;
        // P7
        READ_AB(1, 1); stageA(1, 0, t1 + 2);   BAR_MID; MFMA16(0); BAR_END;
        // P8
        READ_A2(1, 1); stageB(1, 1, t1 + 2);   BAR_MID; MFMA16(4); BAR_END_V(6);
    }

    // epilogue iteration: tiles 190 (buf0), 191 (buf1); only A(191,h1) remains to stage
    {
        READ_AB(0, 0); stageA(1, 1, 191);      BAR_MID; MFMA16(0); BAR_END;
        READ_A2(0, 0);                         BAR_MID; MFMA16(4); BAR_END;
        READ_AB(0, 1);                         BAR_MID; MFMA16(0); BAR_END;
        READ_A2(0, 1);                         BAR_MID; MFMA16(4); BAR_END_V(0);
        READ_AB(1, 0);                         BAR_MID; MFMA16(0); BAR_END;
        READ_A2(1, 0);                         BAR_MID; MFMA16(4); BAR_END;
        READ_AB(1, 1);                         BAR_MID; MFMA16(0); BAR_END;
        READ_A2(1, 1);                         BAR_MID; MFMA16(4);
        __builtin_amdgcn_s_setprio(0);
    }

    // C write: out = acc*w11 + bias + residual
    int ci = cip[0];
    float wf = wfinP[b];
    const float* resid = lo + (((size_t)ci * BATCH + b) * SEQ + s0) * HID;
    float* op = out + ((size_t)b * SEQ + s0) * HID;
    #pragma unroll
    for (int n = 0; n < 4; ++n) {
        int col = n0 + wn * 64 + n * 16 + (lane & 15);
        float bs = biasb[b * HID + col];
        #pragma unroll
        for (int m = 0; m < 8; ++m) {
            int rbase = wm * 128 + m * 16 + (lane >> 4) * 4;
            #pragma unroll
            for (int r = 0; r < 4; ++r) {
                op[(size_t)(rbase + r) * HID + col] =
                    acc[m][n][r] * wf + bs + resid[(size_t)(rbase + r) * HID + col];
            }
        }
    }
}

// ---------------- fallback: round-2 128^2 gload_lds GEMM (proven) ----------------
#define BM 128
#define BN 128
#define BK 64
#define NT (KTOT / BK)    // 192

__global__ __launch_bounds__(256, 2) void gemm128_kernel(
    const float* __restrict__ lo, const ushortT* __restrict__ Abf,
    const ushortT* __restrict__ Btp, const float* __restrict__ ratioP,
    const float* __restrict__ wfinP, const float* __restrict__ biasb,
    const int* __restrict__ cip, float* __restrict__ out)
{
    __shared__ ushortT lA[2][BM * BK];
    __shared__ ushortT lB[2][BN * BK];
    int t = threadIdx.x;
    int bid = blockIdx.x;
    int xcd = bid & 7, local = bid >> 3;
    int by = xcd * 16 + (local >> 3);
    int bx = local & 7;
    int b = by >> 4;
    int s0 = (by & 15) << 7;
    int n0 = bx << 7;
    int wid = t >> 6, lane = t & 63;
    int wr = wid >> 1, wc = wid & 1;
    int m16 = lane & 15, kb = lane >> 4;
    int aBase[4], bBase[4], ldsBase[4];
    #pragma unroll
    for (int i = 0; i < 4; ++i) {
        int ci2 = i * 256 + t;
        int row = ci2 >> 3, c = ci2 & 7;
        int sw = c ^ (row & 7);
        aBase[i] = (s0 + row) * HID + sw * 8;
        bBase[i] = (n0 + row) * KTOT + sw * 8;
        ldsBase[i] = i * 2048 + wid * 512;
    }
    int aoff[4][2], boff[4][2];
    #pragma unroll
    for (int i = 0; i < 4; ++i) {
        int ra = wr * 64 + i * 16 + m16;
        int rb = wc * 64 + i * 16 + m16;
        #pragma unroll
        for (int kk = 0; kk < 2; ++kk) {
            aoff[i][kk] = ra * 64 + (((kb + 4 * kk) ^ (ra & 7)) * 8);
            boff[i][kk] = rb * 64 + (((kb + 4 * kk) ^ (rb & 7)) * 8);
        }
    }
    f32x4 acc[4][4];
    #pragma unroll
    for (int i = 0; i < 4; ++i)
        #pragma unroll
        for (int j = 0; j < 4; ++j)
            acc[i][j] = (f32x4){0.f, 0.f, 0.f, 0.f};
    auto stage = [&](int buf, int tk2) {
        int l = tk2 >> 4;
        const ushortT* aT = Abf + (size_t)(l * BATCH + b) * (SEQ * HID) + ((tk2 & 15) << 6);
        const ushortT* bT = Btp + ((size_t)tk2 << 6);
        ushortT* la = &lA[buf][0];
        ushortT* lb = &lB[buf][0];
        #pragma unroll
        for (int i = 0; i < 4; ++i)
            __builtin_amdgcn_global_load_lds(
                (const __attribute__((address_space(1))) void*)(aT + aBase[i]),
                (__attribute__((address_space(3))) void*)(la + ldsBase[i]), 16, 0, 0);
        #pragma unroll
        for (int i = 0; i < 4; ++i)
            __builtin_amdgcn_global_load_lds(
                (const __attribute__((address_space(1))) void*)(bT + bBase[i]),
                (__attribute__((address_space(3))) void*)(lb + ldsBase[i]), 16, 0, 0);
    };
    stage(0, 0);
    __syncthreads();
    for (int tk = 0; tk < NT; ++tk) {
        int cur = tk & 1;
        if (tk + 1 < NT) stage(cur ^ 1, tk + 1);
        bf16x8 av[4][2], bv[4][2];
        #pragma unroll
        for (int i = 0; i < 4; ++i) {
            av[i][0] = *reinterpret_cast<const bf16x8*>(&lA[cur][aoff[i][0]]);
            av[i][1] = *reinterpret_cast<const bf16x8*>(&lA[cur][aoff[i][1]]);
            bv[i][0] = *reinterpret_cast<const bf16x8*>(&lB[cur][boff[i][0]]);
            bv[i][1] = *reinterpret_cast<const bf16x8*>(&lB[cur][boff[i][1]]);
        }
        if ((tk & 15) == 0 && tk) {
            float rr = ratioP[b * 16 + (tk >> 4)];
            #pragma unroll
            for (int i = 0; i < 4; ++i)
                #pragma unroll
                for (int j = 0; j < 4; ++j)
                    acc[i][j] = acc[i][j] * rr;
        }
        #pragma unroll
        for (int kk = 0; kk < 2; ++kk)
            #pragma unroll
            for (int fm = 0; fm < 4; ++fm)
                #pragma unroll
                for (int fn = 0; fn < 4; ++fn)
                    acc[fm][fn] = MM(av[fm][kk], bv[fn][kk], acc[fm][fn]);
        __syncthreads();
    }
    int ci = cip[0];
    float wf = wfinP[b];
    const float* resid = lo + (((size_t)ci * BATCH + b) * SEQ + s0) * HID;
    float* op = out + ((size_t)b * SEQ + s0) * HID;
    #pragma unroll
    for (int fn = 0; fn < 4; ++fn) {
        int col = n0 + wc * 64 + fn * 16 + m16;
        float bs = biasb[b * HID + col];
        #pragma unroll
        for (int fm = 0; fm < 4; ++fm) {
            int rbase = wr * 64 + fm * 16 + kb * 4;
            #pragma unroll
            for (int r = 0; r < 4; ++r) {
                float v = acc[fm][fn][r] * wf + bs + resid[(size_t)(rbase + r) * HID + col];
                op[(size_t)(rbase + r) * HID + col] = v;
            }
        }
    }
}

extern "C" void kernel_launch(void* const* d_in, const int* in_sizes, int n_in,
                              void* d_out, int out_size, void* d_ws, size_t ws_size,
                              hipStream_t stream) {
    const float* lo  = (const float*)d_in[0];
    const float* cw  = (const float*)d_in[1];
    const float* mU  = (const float*)d_in[2];
    const float* mV  = (const float*)d_in[3];
    const float* W1  = (const float*)d_in[4];
    const float* b1  = (const float*)d_in[5];
    const float* lnw = (const float*)d_in[6];
    const float* lnb = (const float*)d_in[7];
    const float* W2  = (const float*)d_in[8];
    const float* b2  = (const float*)d_in[9];
    const float* pW  = (const float*)d_in[10];
    const float* pb  = (const float*)d_in[11];
    const int*   ci  = (const int*)d_in[12];
    float* out = (float*)d_out;

    float* pooled = (float*)d_ws;                          // 98304 f
    float* gateb  = pooled + 98304;
    float* wsc    = gateb + 96;
    float* ratio  = wsc + 96;
    float* wfin   = ratio + 128;
    float* biasb  = wfin + 8;
    ushortT* Btp  = (ushortT*)((char*)d_ws + 458752);      // 25165824 B
    ushortT* Abf  = (ushortT*)((char*)d_ws + 25624576);    // 402653184 B
    const size_t need = 25624576ULL + 402653184ULL;

    int fast = (ws_size >= need) ? 1 : 0;

    hipMemsetAsync(pooled, 0, 98304 * sizeof(float), stream);
    pool_convert_kernel<<<dim3(96, 16), 256, 0, stream>>>(lo, pooled, Abf, fast);
    gate_kernel<<<96, 256, 0, stream>>>(pooled, W1, b1, lnw, lnb, W2, b2, gateb);
    prep_kernel<<<1, 256, 0, stream>>>(cw, mU, mV, gateb, pb, ci, wsc, ratio, wfin, biasb);
    transB_kernel<<<dim3(192, 16), 256, 0, stream>>>(pW, Btp);
    if (fast) {
        gemm8_kernel<<<dim3(256), 512, 0, stream>>>(lo, Abf, Btp, ratio, wfin, biasb, ci, out);
    } else {
        gemm128_kernel<<<dim3(1024), 256, 0, stream>>>(lo, Abf, Btp, ratio, wfin, biasb, ci, out);
    }
}